// Round 7
// baseline (406.599 us; speedup 1.0000x reference)
//
#include <hip/hip_runtime.h>

#define HH 512
#define WW 512
#define HW_ 262144
#define NIMG 16
#define MK 2048
#define CAPB 4096
#define SCAP 32768   // survivor capacity per image
#define SBUFN 768    // per-block survivor staging (>=484 worst-case maxima per 64x64 tile)

static constexpr size_t OFF_B1    = 16777216;   // 16MB
static constexpr size_t OFF_B2    = 33554432;   // 32MB
static constexpr size_t OFF_SMALL = 50331648;   // 48MB
// regions inside buffer A (all written only after A's last read in k_smwnms):
static constexpr size_t OFF_SEL  = 4194304;
static constexpr size_t OFF_BND  = 4325376;
static constexpr size_t OFF_PP   = 4849664;
static constexpr size_t OFF_WXp  = 5111808;
static constexpr size_t OFF_WYp  = 5242880;
static constexpr size_t OFF_LG   = 5373952;
static constexpr size_t OFF_SL   = 5505024;
static constexpr size_t OFF_PMIN = 5636096;
// regions inside B2 (B2 dead after k_match):
static constexpr size_t OFF_HIST = 33554432;            // 4MB
static constexpr size_t OFF_SURV = 33554432 + 4194304;  // 4MB

// per-image counters padded to 128B to kill cacheline serialization
#define CSTRIDE 32

// ---------- helpers ----------
__device__ __forceinline__ float wred64(float v) {
  for (int m = 1; m < 64; m <<= 1) v += __shfl_xor(v, m);
  return v;
}

__device__ __forceinline__ void g25_wave0(float* g) {
  int t = threadIdx.x;
  if (t < 64) {
    float raw = 0.0f;
    if (t < 25) {
      float x = -1.0f + (float)t * (2.0f / 24.0f);
      raw = expf(-(x * x) / 0.5f);
    }
    float s = raw;
    for (int m = 1; m < 64; m <<= 1) s += __shfl_xor(s, m);
    if (t < 25) g[t] = raw / s;
  }
}
__device__ __forceinline__ void w51_wave0(float* wc) {
  int t = threadIdx.x;
  if (t < 51) {
    float x = -2.0f + (float)t * (4.0f / 50.0f);
    wc[t] = expf(-x * x);
  }
}

template<int B>
__device__ __forceinline__ float brsum(float v, float* red) {
  int t = threadIdx.x;
  red[t] = v; __syncthreads();
  for (int s = B >> 1; s > 0; s >>= 1) {
    if (t < s) red[t] += red[t + s];
    __syncthreads();
  }
  float r = red[0]; __syncthreads();
  return r;
}
template<int B>
__device__ __forceinline__ float brmax(float v, float* red) {
  int t = threadIdx.x;
  red[t] = v; __syncthreads();
  for (int s = B >> 1; s > 0; s >>= 1) {
    if (t < s) red[t] = fmaxf(red[t], red[t + s]);
    __syncthreads();
  }
  float r = red[0]; __syncthreads();
  return r;
}

// ---------- pass 1: exp + all three global sums (separable conv trick) ----------
__global__ void __launch_bounds__(256)
k_pre(const float* __restrict__ x, const float* __restrict__ hd, float* A,
      float* sume, float* sumS, float* Zb) {
  __shared__ float g[25];
  __shared__ float red[12];
  int tid = threadIdx.x;
  g25_wave0(g);
  size_t base = (size_t)blockIdx.x * 1024;
  size_t e = base + tid * 4;
  float4 xs = *(const float4*)(x + e);
  float4 hs = *(const float4*)(hd + e);
  __syncthreads();
  int rem = (int)(e & (HW_ - 1));
  int y = rem >> 9, x0 = rem & 511;
  float wv = 0.0f;
  {
    int k0 = y - 499; if (k0 < 0) k0 = 0;
    int k1 = y + 12;  if (k1 > 24) k1 = 24;
    for (int k = k0; k <= k1; k++) wv += g[k];
  }
  float cwv[4], cpv[4];
  {
    int lo = x0 - 487; if (lo < 0) lo = 0;
    int hi = x0;       if (hi > 24) hi = 24;
    float c = 0.0f;
    for (int d = lo; d <= hi; d++) c += g[d];
    cwv[0] = c;
    for (int q = 1; q < 4; q++) {
      int i = x0 + q;
      if (i <= 24) c += g[i];
      if (i >= 488) c -= g[i - 488];
      cwv[q] = c;
    }
  }
  {
    int lo = x0 - 499; if (lo < 0) lo = 0;
    int hi = x0 + 12;  if (hi > 24) hi = 24;
    float c = 0.0f;
    for (int d = lo; d <= hi; d++) c += g[d];
    cpv[0] = c;
    for (int q = 1; q < 4; q++) {
      int i = x0 + q;
      if (i + 12 <= 24) c += g[i + 12];
      if (i >= 500) c -= g[i - 500];
      cpv[q] = c;
    }
  }
  float e0 = expf(xs.x), e1 = expf(xs.y), e2 = expf(xs.z), e3 = expf(xs.w);
  *(float4*)(A + e) = make_float4(e0, e1, e2, e3);
  float r0 = (e0 + e1) + (e2 + e3);
  float r1 = (e0 * cwv[0] + e1 * cwv[1] + e2 * cwv[2] + e3 * cwv[3]) * wv;
  float r2 = (hs.x * cpv[0] + hs.y * cpv[1] + hs.z * cpv[2] + hs.w * cpv[3]) * wv;
  r0 = wred64(r0); r1 = wred64(r1); r2 = wred64(r2);
  int wid = tid >> 6;
  if ((tid & 63) == 0) { red[wid] = r0; red[4 + wid] = r1; red[8 + wid] = r2; }
  __syncthreads();
  if (tid == 0) {
    int img = (int)(base >> 18);
    atomicAdd(&sume[img * CSTRIDE], red[0] + red[1] + red[2] + red[3]);
    atomicAdd(&sumS[img * CSTRIDE], red[4] + red[5] + red[6] + red[7]);
    atomicAdd(&Zb[img * CSTRIDE], red[8] + red[9] + red[10] + red[11]);
  }
}

// ---------- horizontal convs: pure streaming, one row per block ----------
__global__ void __launch_bounds__(256)
k_hconv(const float* __restrict__ A, const float* __restrict__ hd,
        const float* __restrict__ sume, float* b1, float* b2) {
  __shared__ __align__(16) float ta[512];
  __shared__ __align__(16) float th[536];
  __shared__ float g[25];
  int tid = threadIdx.x;
  int blk = blockIdx.x;
  int img = blk >> 9;
  size_t rowoff = (size_t)blk * 512;
  g25_wave0(g);
  ((float2*)ta)[tid] = *(const float2*)(A + rowoff + tid * 2);
  ((float2*)(th + 12))[tid] = *(const float2*)(hd + rowoff + tid * 2);
  if (tid < 12) { th[tid] = 0.0f; th[524 + tid] = 0.0f; }
  __syncthreads();
  float inv = 1.0f / sume[img * CSTRIDE];
  int j = 2 * tid;
  float v1a = 0.0f, v1b = 0.0f;
  if (tid >= 6 && tid <= 249) {
    float w[26];
#pragma unroll
    for (int d = 0; d < 26; d++) w[d] = ta[j - 12 + d];
#pragma unroll
    for (int d = 0; d < 25; d++) {
      v1a = fmaf(g[d], w[d], v1a);
      v1b = fmaf(g[d], w[d + 1], v1b);
    }
  }
  float v2a = 0.0f, v2b = 0.0f;
  {
    float u[26];
#pragma unroll
    for (int d = 0; d < 26; d++) u[d] = th[j + d];
#pragma unroll
    for (int d = 0; d < 25; d++) {
      v2a = fmaf(g[d], u[d], v2a);
      v2b = fmaf(g[d], u[d + 1], v2b);
    }
  }
  ((float2*)b1)[blk * 256 + tid] = make_float2(v1a * inv, v1b * inv);
  ((float2*)b2)[blk * 256 + tid] = make_float2(v2a, v2b);
}

// fused vertical convs + KL reduction, LDS-tiled
__global__ void __launch_bounds__(256)
k_match(const float* __restrict__ b1, const float* __restrict__ b2,
        const float* __restrict__ sume, const float* sumS, const float* Zb,
        float* macc) {
  __shared__ float g[25];
  __shared__ float t1[88 * 64];
  __shared__ float t2[88 * 64];
  __shared__ float red4[4];
  g25_wave0(g);
  int blk = blockIdx.x;
  int img = blk >> 6;
  int ty = (blk >> 3) & 7;
  int tx = blk & 7;
  int y0 = ty * 64, x0 = tx * 64;
  const float* base1 = b1 + (size_t)img * HW_;
  const float* base2 = b2 + (size_t)img * HW_;
  for (int i = threadIdx.x; i < 88 * 64; i += 256) {
    int r = i >> 6, c = i & 63;
    int y = y0 + r - 12;
    float v1 = 0.0f, v2 = 0.0f;
    if (y >= 0 && y < 512) {
      size_t o = (size_t)y * 512 + x0 + c;
      v1 = base1[o]; v2 = base2[o];
    }
    t1[i] = v1; t2[i] = v2;
  }
  __syncthreads();
  float Z = Zb[img * CSTRIDE];
  float inv = 1.0f / sume[img * CSTRIDE];
  float logS = logf(sumS[img * CSTRIDE] * inv + (float)HW_ * 1e-8f);
  float acc = 0.0f;
  for (int k0 = 0; k0 < 16; k0++) {
    int i = threadIdx.x + k0 * 256;
    int r = i >> 6, c = i & 63;
    float s = 0.0f, sd = 0.0f;
#pragma unroll
    for (int k = 0; k < 25; k++) {
      s  = fmaf(g[k], t1[(r + k) * 64 + c], s);
      sd = fmaf(g[k], t2[(r + k) * 64 + c], sd);
    }
    float p = sd / Z;
    if (p > 0.0f)
      acc += p * (logf(fmaxf(p, 1e-30f)) - (logf(s + 1e-8f) - logS));
  }
  acc = wred64(acc);
  if ((threadIdx.x & 63) == 0) red4[threadIdx.x >> 6] = acc;
  __syncthreads();
  if (threadIdx.x == 0)
    atomicAdd(macc, red4[0] + red4[1] + red4[2] + red4[3]);
}

// ---------- keypoint sampling ----------
__global__ void __launch_bounds__(256)
k_h51(const float* __restrict__ A, const float* __restrict__ sume, float* out) {
  __shared__ float wc[51];
  __shared__ __align__(16) float ta[564];
  int tid = threadIdx.x;
  int blk = blockIdx.x;
  int img = blk >> 9;
  size_t rowoff = (size_t)blk * 512;
  w51_wave0(wc);
  float s1 = 1e4f / sume[img * CSTRIDE];
  for (int i = tid; i < 562; i += 256) {
    int j = i - 25;
    ta[i] = ((unsigned)j < 512u) ? fmaf(A[rowoff + j], s1, 1e-2f) : 0.0f;
  }
  __syncthreads();
  int j = 2 * tid;
  float w[52];
#pragma unroll
  for (int d = 0; d < 52; d++) w[d] = ta[j + d];
  float va = 0.0f, vb = 0.0f;
#pragma unroll
  for (int d = 0; d < 51; d++) {
    va = fmaf(wc[d], w[d], va);
    vb = fmaf(wc[d], w[d + 1], vb);
  }
  ((float2*)out)[blk * 256 + tid] = make_float2(va, vb);
}

// fused: vertical 51-tap + coverage reweight + 5x5 NMS + block-aggregated
// survivor compaction + histogram. 512 threads, float4 LDS processing.
__global__ void __launch_bounds__(512)
k_smwnms(const float* __restrict__ A, const float* __restrict__ sume,
         const float* __restrict__ b1,
         unsigned long long* surv, unsigned* scnt, unsigned* hist) {
  __shared__ float wc[51];
  __shared__ __align__(16) float tb1[118 * 68];
  __shared__ __align__(16) float tsm[68 * 68];
  __shared__ unsigned long long sbuf[SBUFN];
  __shared__ unsigned lcnt;
  __shared__ unsigned gbase;
  int tid = threadIdx.x;
  w51_wave0(wc);
  if (tid == 0) lcnt = 0;
  int blk = blockIdx.x;
  int img = blk >> 6;
  int ty = (blk >> 3) & 7;
  int tx = blk & 7;
  int y0 = ty * 64, x0 = tx * 64;
  const float* base = b1 + (size_t)img * HW_;
  // B1 rows y0-27..y0+90, cols x0-2..x0+65 (zero OOB)
  for (int i = tid; i < 118 * 68; i += 512) {
    int r = i / 68, c = i - r * 68;
    int y = y0 + r - 27, x = x0 + c - 2;
    tb1[i] = (y >= 0 && y < 512 && x >= 0 && x < 512)
                 ? base[(size_t)y * 512 + x] : 0.0f;
  }
  __syncthreads();
  float inv = 1.0f / sume[img * CSTRIDE];
  const float* abase = A + (size_t)img * HW_;
  // conv: 68 rows x 17 float4-col-groups of the 68x68 smw halo tile
  for (int gidx = tid; gidx < 68 * 17; gidx += 512) {
    int r = gidx / 17, cg = gidx - r * 17;
    const float4* col = (const float4*)tb1 + r * 17 + cg;
    float4 acc = make_float4(0.0f, 0.0f, 0.0f, 0.0f);
    for (int k = 0; k < 51; k++) {
      float4 t = col[k * 17];
      acc.x = fmaf(wc[k], t.x, acc.x);
      acc.y = fmaf(wc[k], t.y, acc.y);
      acc.z = fmaf(wc[k], t.z, acc.z);
      acc.w = fmaf(wc[k], t.w, acc.w);
    }
    int y = y0 + r - 2;
    int xb = x0 + cg * 4 - 2;
    float den[4] = {acc.x, acc.y, acc.z, acc.w};
    float res[4];
#pragma unroll
    for (int j = 0; j < 4; j++) {
      int x = xb + j;
      float o = -3.4e38f;
      if (y >= 0 && y < 512 && x >= 0 && x < 512)
        o = (abase[(size_t)y * 512 + x] * inv) / sqrtf(den[j] + 1e-8f);
      res[j] = o;
    }
    *((float4*)tsm + gidx) = make_float4(res[0], res[1], res[2], res[3]);
  }
  __syncthreads();
  // NMS 5x5: 64 rows x 16 col-groups; window via two float4 reads per row
  for (int gidx = tid; gidx < 64 * 16; gidx += 512) {
    int r = gidx >> 4, cg = gidx & 15;
    float v[4], M[4];
#pragma unroll
    for (int j = 0; j < 4; j++) M[j] = -3.4e38f;
#pragma unroll
    for (int dr = 0; dr < 5; dr++) {
      float4 q0 = *((const float4*)tsm + (r + dr) * 17 + cg);
      float4 q1 = *((const float4*)tsm + (r + dr) * 17 + cg + 1);
      float w0 = q0.x, w1 = q0.y, w2 = q0.z, w3 = q0.w;
      float w4 = q1.x, w5 = q1.y, w6 = q1.z, w7 = q1.w;
      M[0] = fmaxf(M[0], fmaxf(fmaxf(w0, w1), fmaxf(w2, fmaxf(w3, w4))));
      M[1] = fmaxf(M[1], fmaxf(fmaxf(w1, w2), fmaxf(w3, fmaxf(w4, w5))));
      M[2] = fmaxf(M[2], fmaxf(fmaxf(w2, w3), fmaxf(w4, fmaxf(w5, w6))));
      M[3] = fmaxf(M[3], fmaxf(fmaxf(w3, w4), fmaxf(w5, fmaxf(w6, w7))));
      if (dr == 2) { v[0] = w2; v[1] = w3; v[2] = w4; v[3] = w5; }
    }
#pragma unroll
    for (int j = 0; j < 4; j++) {
      bool keep = (v[j] == M[j]) && (v[j] != 0.0f);
      if (keep) {
        unsigned p = atomicAdd(&lcnt, 1u);   // LDS atomic: cheap
        unsigned bits = __float_as_uint(v[j]);
        unsigned idx = (unsigned)((y0 + r) * 512 + x0 + cg * 4 + j);
        if (p < SBUFN)
          sbuf[p] = ((unsigned long long)bits << 32) |
                    (unsigned long long)(idx ^ 0xFFFFFFFFu);
        atomicAdd(&hist[(size_t)img * 65536 + (bits >> 16)], 1u);
      }
    }
  }
  __syncthreads();
  unsigned total = lcnt; if (total > SBUFN) total = SBUFN;
  if (tid == 0) gbase = atomicAdd(&scnt[img * CSTRIDE], total);
  __syncthreads();
  unsigned gb = gbase;
  for (unsigned i = tid; i < total; i += 512) {
    unsigned p = gb + i;
    if (p < SCAP) surv[(size_t)img * SCAP + p] = sbuf[i];
  }
}

__global__ void k_thresh(const unsigned* __restrict__ hist, unsigned* Tb, unsigned* needb) {
  int img = blockIdx.x;
  const unsigned* h = hist + (size_t)img * 65536;
  __shared__ unsigned part[256];
  __shared__ unsigned scan[257];
  int t = threadIdx.x;
  unsigned s = 0;
  for (int k = 0; k < 256; k++) {
    int bin = 65535 - (t * 256 + k);
    s += (bin == 0) ? 0x00100000u : h[bin];
  }
  part[t] = s; __syncthreads();
  if (t == 0) {
    unsigned c = 0;
    for (int k = 0; k < 256; k++) { scan[k] = c; c += part[k]; }
    scan[256] = c;
  }
  __syncthreads();
  unsigned pre = scan[t];
  if (pre < MK && pre + part[t] >= MK) {
    unsigned c = pre;
    for (int k = 0; k < 256; k++) {
      int bin = 65535 - (t * 256 + k);
      unsigned cnt = (bin == 0) ? 0x00100000u : h[bin];
      if (c + cnt >= MK) { Tb[img * CSTRIDE] = (unsigned)bin; needb[img * CSTRIDE] = MK - c; break; }
      c += cnt;
    }
  }
}

// compaction from survivor list
__global__ void k_collect(const unsigned long long* __restrict__ surv,
                          const unsigned* __restrict__ scnt,
                          const unsigned* __restrict__ Tb,
                          unsigned* selcnt, unsigned* sel,
                          unsigned* bcnt, unsigned long long* bnd) {
  int blk = blockIdx.x;
  int img = blk >> 7;
  int i = (blk & 127) * 256 + threadIdx.x;
  unsigned cnt = scnt[img * CSTRIDE]; if (cnt > SCAP) cnt = SCAP;
  unsigned long long entry = ((unsigned)i < cnt) ? surv[(size_t)img * SCAP + i] : 0ull;
  unsigned bits = (unsigned)(entry >> 32);
  unsigned bin = bits >> 16;
  unsigned T = Tb[img * CSTRIDE];
  bool ok = (unsigned)i < cnt;
  bool c1 = ok && (bin > T);
  bool c2 = ok && (bin == T);
  int lane = threadIdx.x & 63;
  unsigned long long lowmask = (1ull << lane) - 1ull;

  unsigned long long m1 = __ballot(c1);
  if (m1) {
    int leader = __ffsll(m1) - 1;
    unsigned base = 0;
    if (lane == leader) base = atomicAdd(&selcnt[img * CSTRIDE], (unsigned)__popcll(m1));
    base = __shfl(base, leader);
    if (c1) {
      unsigned p = base + (unsigned)__popcll(m1 & lowmask);
      if (p < MK) sel[img * MK + p] = (unsigned)(entry & 0xFFFFFFFFull) ^ 0xFFFFFFFFu;
    }
  }
  unsigned long long m2 = __ballot(c2);
  if (m2) {
    int leader = __ffsll(m2) - 1;
    unsigned base = 0;
    if (lane == leader) base = atomicAdd(&bcnt[img * CSTRIDE], (unsigned)__popcll(m2));
    base = __shfl(base, leader);
    if (c2) {
      unsigned p = base + (unsigned)__popcll(m2 & lowmask);
      if (p < CAPB) bnd[(size_t)img * CAPB + p] = entry;
    }
  }
}

__global__ void __launch_bounds__(1024)
k_finsel(const unsigned long long* __restrict__ bnd, const unsigned* bcnt,
         const unsigned* needb, const unsigned* selcnt, unsigned* sel) {
  int img = blockIdx.x;
  __shared__ unsigned long long key[CAPB];
  unsigned bn = bcnt[img * CSTRIDE];
  int n = (bn < CAPB) ? (int)bn : CAPB;
  int np2 = 2;
  while (np2 < n) np2 <<= 1;
  int t = threadIdx.x;
  for (int k = t; k < np2; k += 1024)
    key[k] = (k < n) ? bnd[(size_t)img * CAPB + k] : 0ull;
  __syncthreads();
  for (int sz = 2; sz <= np2; sz <<= 1) {
    for (int st = sz >> 1; st > 0; st >>= 1) {
      for (int i = t; i < np2; i += 1024) {
        int l = i ^ st;
        if (l > i) {
          unsigned long long a = key[i], b = key[l];
          bool up = ((i & sz) == 0);
          if (up ? (a < b) : (a > b)) { key[i] = b; key[l] = a; }
        }
      }
      __syncthreads();
    }
  }
  unsigned c1 = selcnt[img * CSTRIDE]; if (c1 > MK) c1 = MK;
  unsigned need = needb[img * CSTRIDE];
  unsigned kk = need; if (kk > MK - c1) kk = MK - c1;
  for (unsigned m = t; m < MK - c1; m += 1024) {
    unsigned v = 0u;
    if (m < kk && m < (unsigned)n)
      v = (unsigned)(key[m] & 0xFFFFFFFFull) ^ 0xFFFFFFFFu;
    sel[img * MK + c1 + m] = v;
  }
}

// ---------- sparse loss ----------
__global__ void k_prep(const unsigned* __restrict__ sel, const float* __restrict__ scoremap,
                       const float* __restrict__ gtA, const float* __restrict__ gtB,
                       const float* __restrict__ vA, const float* __restrict__ vB,
                       float2* pp, float* wx, float* wy, float* lg, float* sl) {
  int t = blockIdx.x * 256 + threadIdx.x;  // 0..32767
  int img = t >> 11;
  unsigned idx = sel[t] & (HW_ - 1);
  int h = idx >> 9, w = idx & 511;
  pp[t] = make_float2((w + 0.5f) * (2.0f / 512.0f) - 1.0f,
                      (h + 0.5f) * (2.0f / 512.0f) - 1.0f);
  int b = (img < 8) ? img : img - 8;
  const float* gt = (img < 8) ? gtA : gtB;
  const float* vv = (img < 8) ? vA : vB;
  size_t pix = (size_t)b * HW_ + idx;
  float2 gxy = *(const float2*)(gt + pix * 4 + 2);
  wx[t] = gxy.x;
  wy[t] = gxy.y;
  lg[t] = (vv[pix] > 0.0f) ? 1.0f : 0.0f;
  sl[t] = scoremap[(size_t)img * HW_ + idx];
}

// split 4-way over opponents, 8 independent min accumulators per thread
__global__ void __launch_bounds__(256)
k_mindist(const float2* __restrict__ pp,
          const float* __restrict__ wx, const float* __restrict__ wy,
          float* pmin) {
  __shared__ float2 opp[512];
  int blk = blockIdx.x;
  int img = blk >> 5;
  int qc = (blk >> 2) & 7;
  int oc = blk & 3;
  const float2* ob = pp + (size_t)(img ^ 8) * MK + oc * 512;
  for (int k = threadIdx.x; k < 512; k += 256) opp[k] = ob[k];
  __syncthreads();
  int m = img * MK + qc * 256 + threadIdx.x;
  float ax = wx[m], ay = wy[m];
  float d[8];
#pragma unroll
  for (int u = 0; u < 8; u++) d[u] = 3.4e38f;
  for (int n = 0; n < 512; n += 8) {
#pragma unroll
    for (int u = 0; u < 8; u++) {
      float2 o = opp[n + u];
      float dx = ax - o.x, dy = ay - o.y;
      d[u] = fminf(d[u], fmaf(dx, dx, dy * dy));
    }
  }
  float d2 = fminf(fminf(fminf(d[0], d[1]), fminf(d[2], d[3])),
                   fminf(fminf(d[4], d[5]), fminf(d[6], d[7])));
  pmin[oc * (NIMG * MK) + m] = d2;
}

__global__ void __launch_bounds__(1024)
k_loss(const float* __restrict__ sl, const float* __restrict__ lg,
       const float* __restrict__ pmin, float* sacc) {
  int img = blockIdx.x;
  __shared__ float red[1024];
  int t = threadIdx.x;
  int i0 = img * MK + t, i1 = i0 + 1024;
  float s0 = sl[i0], s1 = sl[i1];
  float g0 = lg[i0], g1 = lg[i1];
  float l0 = (g0 > 0.0f) ? s0 : -1e9f;
  float l1 = (g1 > 0.0f) ? s1 : -1e9f;
  float mx = brmax<1024>(fmaxf(l0, l1), red);
  float se = brsum<1024>(expf(l0 - mx) + expf(l1 - mx), red);
  float lse = mx + logf(se);
  const int ST = NIMG * MK;
  float a = 0.0f;
  if (g0 > 0.0f) {
    float mn = fminf(fminf(pmin[i0], pmin[ST + i0]),
                     fminf(pmin[2 * ST + i0], pmin[3 * ST + i0]));
    float r0 = expf(-100.0f * sqrtf(mn + 1e-12f));
    a += r0 * (s0 - lse);
  }
  if (g1 > 0.0f) {
    float mn = fminf(fminf(pmin[i1], pmin[ST + i1]),
                     fminf(pmin[2 * ST + i1], pmin[3 * ST + i1]));
    float r1 = expf(-100.0f * sqrtf(mn + 1e-12f));
    a += r1 * (s1 - lse);
  }
  float tot = brsum<1024>(a, red);
  if (t == 0) atomicAdd(sacc, -tot);
}

__global__ void k_out(const float* macc, const float* sacc, float* out) {
  out[0] = sacc[0] + macc[0] * (1.0f / 16.0f);
}

// ---------- launch ----------
extern "C" void kernel_launch(void* const* d_in, const int* in_sizes, int n_in,
                              void* d_out, int out_size, void* d_ws, size_t ws_size,
                              hipStream_t stream) {
  const float* scoremap = (const float*)d_in[0];
  const float* gtA = (const float*)d_in[1];
  const float* gtB = (const float*)d_in[2];
  const float* vA  = (const float*)d_in[3];
  const float* vB  = (const float*)d_in[4];
  const float* hd  = (const float*)d_in[5];

  char* ws = (char*)d_ws;
  float* A  = (float*)(ws);
  float* B1 = (float*)(ws + OFF_B1);

  char* sm = ws + OFF_SMALL;
  float*    sume   = (float*)(sm + 0);
  float*    sumS   = (float*)(sm + 2048);
  float*    Zb     = (float*)(sm + 4096);
  unsigned* Tb     = (unsigned*)(sm + 6144);
  unsigned* needb  = (unsigned*)(sm + 8192);
  unsigned* selcnt = (unsigned*)(sm + 10240);
  unsigned* bcnt   = (unsigned*)(sm + 12288);
  float*    macc   = (float*)(sm + 14336);
  float*    sacc   = (float*)(sm + 14464);
  unsigned* scnt   = (unsigned*)(sm + 16384);

  unsigned* hist = (unsigned*)(ws + OFF_HIST);
  unsigned long long* surv = (unsigned long long*)(ws + OFF_SURV);
  unsigned* sel  = (unsigned*)(ws + OFF_SEL);
  unsigned long long* bnd = (unsigned long long*)(ws + OFF_BND);
  float2* pp = (float2*)(ws + OFF_PP);
  float* wx = (float*)(ws + OFF_WXp);
  float* wy = (float*)(ws + OFF_WYp);
  float* lg = (float*)(ws + OFF_LG);
  float* sl = (float*)(ws + OFF_SL);
  float* pmin = (float*)(ws + OFF_PMIN);
  float* B2 = (float*)(ws + 33554432);

  float* out = (float*)d_out;

  hipMemsetAsync(sm, 0, 32768, stream);

  // pass 1: exp + sume/sumS/Zb (separable conv sums)
  k_pre<<<4096, 256, 0, stream>>>(scoremap, hd, A, sume, sumS, Zb);

  // matchability
  k_hconv<<<8192, 256, 0, stream>>>(A, hd, sume, B1, B2);
  k_match<<<1024, 256, 0, stream>>>(B1, B2, sume, sumS, Zb, macc);

  // coverage conv (h) -> B1'; hist/surv live in B2 (dead after k_match)
  k_h51<<<8192, 256, 0, stream>>>(A, sume, B1);
  hipMemsetAsync(ws + OFF_HIST, 0, (size_t)16 * 65536 * 4, stream);

  // fused vconv+reweight+NMS+compaction+hist (512 threads, float4 LDS)
  k_smwnms<<<1024, 512, 0, stream>>>(A, sume, B1, surv, scnt, hist);
  k_thresh<<<16, 256, 0, stream>>>(hist, Tb, needb);
  k_collect<<<2048, 256, 0, stream>>>(surv, scnt, Tb, selcnt, sel, bcnt, bnd);
  k_finsel<<<16, 1024, 0, stream>>>(bnd, bcnt, needb, selcnt, sel);

  // sparse loss
  k_prep<<<128, 256, 0, stream>>>(sel, scoremap, gtA, gtB, vA, vB, pp, wx, wy, lg, sl);
  k_mindist<<<512, 256, 0, stream>>>(pp, wx, wy, pmin);
  k_loss<<<16, 1024, 0, stream>>>(sl, lg, pmin, sacc);
  k_out<<<1, 1, 0, stream>>>(macc, sacc, out);
}

// Round 8
// 335.317 us; speedup vs baseline: 1.2126x; 1.2126x over previous
//
#include <hip/hip_runtime.h>

#define HH 512
#define WW 512
#define HW_ 262144
#define NIMG 16
#define MK 2048
#define CAPB 4096
#define SCAP 32768   // survivor capacity per image
#define SBUFN 768    // per-block survivor staging (>=484 worst-case maxima per 64x64 tile)

static constexpr size_t OFF_B1    = 16777216;   // 16MB
static constexpr size_t OFF_B2    = 33554432;   // 32MB
static constexpr size_t OFF_SMALL = 50331648;   // 48MB
// regions inside buffer A (all written only after A's last read in k_smwnms):
static constexpr size_t OFF_SEL  = 4194304;
static constexpr size_t OFF_BND  = 4325376;
static constexpr size_t OFF_PP   = 4849664;
static constexpr size_t OFF_WXp  = 5111808;
static constexpr size_t OFF_WYp  = 5242880;
static constexpr size_t OFF_LG   = 5373952;
static constexpr size_t OFF_SL   = 5505024;
static constexpr size_t OFF_PMIN = 5636096;
// regions inside B2 (B2 dead after k_match):
static constexpr size_t OFF_HIST = 33554432;            // 4MB
static constexpr size_t OFF_SURV = 33554432 + 4194304;  // 4MB

// per-image counters padded to 128B to kill cacheline serialization
#define CSTRIDE 32

// ---------- helpers ----------
__device__ __forceinline__ float wred64(float v) {
  for (int m = 1; m < 64; m <<= 1) v += __shfl_xor(v, m);
  return v;
}

__device__ __forceinline__ void g25_wave0(float* g) {
  int t = threadIdx.x;
  if (t < 64) {
    float raw = 0.0f;
    if (t < 25) {
      float x = -1.0f + (float)t * (2.0f / 24.0f);
      raw = expf(-(x * x) / 0.5f);
    }
    float s = raw;
    for (int m = 1; m < 64; m <<= 1) s += __shfl_xor(s, m);
    if (t < 25) g[t] = raw / s;
  }
}
__device__ __forceinline__ void w51_wave0(float* wc) {
  int t = threadIdx.x;
  if (t < 51) {
    float x = -2.0f + (float)t * (4.0f / 50.0f);
    wc[t] = expf(-x * x);
  }
}

template<int B>
__device__ __forceinline__ float brsum(float v, float* red) {
  int t = threadIdx.x;
  red[t] = v; __syncthreads();
  for (int s = B >> 1; s > 0; s >>= 1) {
    if (t < s) red[t] += red[t + s];
    __syncthreads();
  }
  float r = red[0]; __syncthreads();
  return r;
}
template<int B>
__device__ __forceinline__ float brmax(float v, float* red) {
  int t = threadIdx.x;
  red[t] = v; __syncthreads();
  for (int s = B >> 1; s > 0; s >>= 1) {
    if (t < s) red[t] = fmaxf(red[t], red[t + s]);
    __syncthreads();
  }
  float r = red[0]; __syncthreads();
  return r;
}

// ---------- pass 1: exp + all three global sums (separable conv trick) ----------
__global__ void __launch_bounds__(256)
k_pre(const float* __restrict__ x, const float* __restrict__ hd, float* A,
      float* sume, float* sumS, float* Zb) {
  __shared__ float g[25];
  __shared__ float red[12];
  int tid = threadIdx.x;
  g25_wave0(g);
  size_t base = (size_t)blockIdx.x * 1024;
  size_t e = base + tid * 4;
  float4 xs = *(const float4*)(x + e);
  float4 hs = *(const float4*)(hd + e);
  __syncthreads();
  int rem = (int)(e & (HW_ - 1));
  int y = rem >> 9, x0 = rem & 511;
  float wv = 0.0f;
  {
    int k0 = y - 499; if (k0 < 0) k0 = 0;
    int k1 = y + 12;  if (k1 > 24) k1 = 24;
    for (int k = k0; k <= k1; k++) wv += g[k];
  }
  float cwv[4], cpv[4];
  {
    int lo = x0 - 487; if (lo < 0) lo = 0;
    int hi = x0;       if (hi > 24) hi = 24;
    float c = 0.0f;
    for (int d = lo; d <= hi; d++) c += g[d];
    cwv[0] = c;
    for (int q = 1; q < 4; q++) {
      int i = x0 + q;
      if (i <= 24) c += g[i];
      if (i >= 488) c -= g[i - 488];
      cwv[q] = c;
    }
  }
  {
    int lo = x0 - 499; if (lo < 0) lo = 0;
    int hi = x0 + 12;  if (hi > 24) hi = 24;
    float c = 0.0f;
    for (int d = lo; d <= hi; d++) c += g[d];
    cpv[0] = c;
    for (int q = 1; q < 4; q++) {
      int i = x0 + q;
      if (i + 12 <= 24) c += g[i + 12];
      if (i >= 500) c -= g[i - 500];
      cpv[q] = c;
    }
  }
  float e0 = expf(xs.x), e1 = expf(xs.y), e2 = expf(xs.z), e3 = expf(xs.w);
  *(float4*)(A + e) = make_float4(e0, e1, e2, e3);
  float r0 = (e0 + e1) + (e2 + e3);
  float r1 = (e0 * cwv[0] + e1 * cwv[1] + e2 * cwv[2] + e3 * cwv[3]) * wv;
  float r2 = (hs.x * cpv[0] + hs.y * cpv[1] + hs.z * cpv[2] + hs.w * cpv[3]) * wv;
  r0 = wred64(r0); r1 = wred64(r1); r2 = wred64(r2);
  int wid = tid >> 6;
  if ((tid & 63) == 0) { red[wid] = r0; red[4 + wid] = r1; red[8 + wid] = r2; }
  __syncthreads();
  if (tid == 0) {
    int img = (int)(base >> 18);
    atomicAdd(&sume[img * CSTRIDE], red[0] + red[1] + red[2] + red[3]);
    atomicAdd(&sumS[img * CSTRIDE], red[4] + red[5] + red[6] + red[7]);
    atomicAdd(&Zb[img * CSTRIDE], red[8] + red[9] + red[10] + red[11]);
  }
}

// ---------- horizontal convs: pure streaming, one row per block ----------
__global__ void __launch_bounds__(256)
k_hconv(const float* __restrict__ A, const float* __restrict__ hd,
        const float* __restrict__ sume, float* b1, float* b2) {
  __shared__ __align__(16) float ta[512];
  __shared__ __align__(16) float th[536];
  __shared__ float g[25];
  int tid = threadIdx.x;
  int blk = blockIdx.x;
  int img = blk >> 9;
  size_t rowoff = (size_t)blk * 512;
  g25_wave0(g);
  ((float2*)ta)[tid] = *(const float2*)(A + rowoff + tid * 2);
  ((float2*)(th + 12))[tid] = *(const float2*)(hd + rowoff + tid * 2);
  if (tid < 12) { th[tid] = 0.0f; th[524 + tid] = 0.0f; }
  __syncthreads();
  float inv = 1.0f / sume[img * CSTRIDE];
  int j = 2 * tid;
  float v1a = 0.0f, v1b = 0.0f;
  if (tid >= 6 && tid <= 249) {
    float w[26];
#pragma unroll
    for (int d = 0; d < 26; d++) w[d] = ta[j - 12 + d];
#pragma unroll
    for (int d = 0; d < 25; d++) {
      v1a = fmaf(g[d], w[d], v1a);
      v1b = fmaf(g[d], w[d + 1], v1b);
    }
  }
  float v2a = 0.0f, v2b = 0.0f;
  {
    float u[26];
#pragma unroll
    for (int d = 0; d < 26; d++) u[d] = th[j + d];
#pragma unroll
    for (int d = 0; d < 25; d++) {
      v2a = fmaf(g[d], u[d], v2a);
      v2b = fmaf(g[d], u[d + 1], v2b);
    }
  }
  ((float2*)b1)[blk * 256 + tid] = make_float2(v1a * inv, v1b * inv);
  ((float2*)b2)[blk * 256 + tid] = make_float2(v2a, v2b);
}

// fused vertical convs + KL reduction, LDS-tiled
__global__ void __launch_bounds__(256)
k_match(const float* __restrict__ b1, const float* __restrict__ b2,
        const float* __restrict__ sume, const float* sumS, const float* Zb,
        float* macc) {
  __shared__ float g[25];
  __shared__ float t1[88 * 64];
  __shared__ float t2[88 * 64];
  __shared__ float red4[4];
  g25_wave0(g);
  int blk = blockIdx.x;
  int img = blk >> 6;
  int ty = (blk >> 3) & 7;
  int tx = blk & 7;
  int y0 = ty * 64, x0 = tx * 64;
  const float* base1 = b1 + (size_t)img * HW_;
  const float* base2 = b2 + (size_t)img * HW_;
  for (int i = threadIdx.x; i < 88 * 64; i += 256) {
    int r = i >> 6, c = i & 63;
    int y = y0 + r - 12;
    float v1 = 0.0f, v2 = 0.0f;
    if (y >= 0 && y < 512) {
      size_t o = (size_t)y * 512 + x0 + c;
      v1 = base1[o]; v2 = base2[o];
    }
    t1[i] = v1; t2[i] = v2;
  }
  __syncthreads();
  float Z = Zb[img * CSTRIDE];
  float inv = 1.0f / sume[img * CSTRIDE];
  float logS = logf(sumS[img * CSTRIDE] * inv + (float)HW_ * 1e-8f);
  float acc = 0.0f;
  for (int k0 = 0; k0 < 16; k0++) {
    int i = threadIdx.x + k0 * 256;
    int r = i >> 6, c = i & 63;
    float s = 0.0f, sd = 0.0f;
#pragma unroll
    for (int k = 0; k < 25; k++) {
      s  = fmaf(g[k], t1[(r + k) * 64 + c], s);
      sd = fmaf(g[k], t2[(r + k) * 64 + c], sd);
    }
    float p = sd / Z;
    if (p > 0.0f)
      acc += p * (logf(fmaxf(p, 1e-30f)) - (logf(s + 1e-8f) - logS));
  }
  acc = wred64(acc);
  if ((threadIdx.x & 63) == 0) red4[threadIdx.x >> 6] = acc;
  __syncthreads();
  if (threadIdx.x == 0)
    atomicAdd(macc, red4[0] + red4[1] + red4[2] + red4[3]);
}

// ---------- keypoint sampling ----------
__global__ void __launch_bounds__(256)
k_h51(const float* __restrict__ A, const float* __restrict__ sume, float* out) {
  __shared__ float wc[51];
  __shared__ __align__(16) float ta[564];
  int tid = threadIdx.x;
  int blk = blockIdx.x;
  int img = blk >> 9;
  size_t rowoff = (size_t)blk * 512;
  w51_wave0(wc);
  float s1 = 1e4f / sume[img * CSTRIDE];
  for (int i = tid; i < 562; i += 256) {
    int j = i - 25;
    ta[i] = ((unsigned)j < 512u) ? fmaf(A[rowoff + j], s1, 1e-2f) : 0.0f;
  }
  __syncthreads();
  int j = 2 * tid;
  float w[52];
#pragma unroll
  for (int d = 0; d < 52; d++) w[d] = ta[j + d];
  float va = 0.0f, vb = 0.0f;
#pragma unroll
  for (int d = 0; d < 51; d++) {
    va = fmaf(wc[d], w[d], va);
    vb = fmaf(wc[d], w[d + 1], vb);
  }
  ((float2*)out)[blk * 256 + tid] = make_float2(va, vb);
}

// fused: vertical 51-tap + coverage reweight + 5x5 NMS + block-aggregated
// survivor compaction + histogram. 512 threads, SCALAR stride-1 LDS indexing
// (conflict-free); LDS-atomic survivor staging; one global atomic per block.
__global__ void __launch_bounds__(512)
k_smwnms(const float* __restrict__ A, const float* __restrict__ sume,
         const float* __restrict__ b1,
         unsigned long long* surv, unsigned* scnt, unsigned* hist) {
  __shared__ float wc[51];
  __shared__ float tb1[118 * 68];
  __shared__ float tsm[68 * 68];
  __shared__ unsigned long long sbuf[SBUFN];
  __shared__ unsigned lcnt;
  __shared__ unsigned gbase;
  int tid = threadIdx.x;
  w51_wave0(wc);
  if (tid == 0) lcnt = 0;
  int blk = blockIdx.x;
  int img = blk >> 6;
  int ty = (blk >> 3) & 7;
  int tx = blk & 7;
  int y0 = ty * 64, x0 = tx * 64;
  const float* base = b1 + (size_t)img * HW_;
  // B1 rows y0-27..y0+90, cols x0-2..x0+65 (zero OOB)
  for (int i = tid; i < 118 * 68; i += 512) {
    int r = i / 68, c = i - r * 68;
    int y = y0 + r - 27, x = x0 + c - 2;
    tb1[i] = (y >= 0 && y < 512 && x >= 0 && x < 512)
                 ? base[(size_t)y * 512 + x] : 0.0f;
  }
  __syncthreads();
  float inv = 1.0f / sume[img * CSTRIDE];
  const float* abase = A + (size_t)img * HW_;
  // smw on 68x68 halo tile (-inf outside image); scalar stride-1 LDS reads
  for (int i = tid; i < 68 * 68; i += 512) {
    int r = i / 68, c = i - r * 68;
    int y = y0 + r - 2, x = x0 + c - 2;
    float res = -3.4e38f;
    if (y >= 0 && y < 512 && x >= 0 && x < 512) {
      float v = 0.0f;
#pragma unroll
      for (int k = 0; k < 51; k++) v = fmaf(wc[k], tb1[(r + k) * 68 + c], v);
      res = (abase[(size_t)y * 512 + x] * inv) / sqrtf(v + 1e-8f);
    }
    tsm[i] = res;
  }
  __syncthreads();
  // 5x5 NMS from LDS; LDS-atomic staging of survivors
  for (int k0 = 0; k0 < 8; k0++) {
    int i = tid + k0 * 512;
    int r = i >> 6, c = i & 63;
    float v = tsm[(r + 2) * 68 + (c + 2)];
    float mx = v;
#pragma unroll
    for (int dy = 0; dy < 5; dy++)
#pragma unroll
      for (int dx = 0; dx < 5; dx++)
        mx = fmaxf(mx, tsm[(r + dy) * 68 + (c + dx)]);
    bool keep = (v == mx) && (v != 0.0f);
    if (keep) {
      unsigned p = atomicAdd(&lcnt, 1u);   // LDS atomic: cheap
      unsigned bits = __float_as_uint(v);
      unsigned idx = (unsigned)((y0 + r) * 512 + x0 + c);
      if (p < SBUFN)
        sbuf[p] = ((unsigned long long)bits << 32) |
                  (unsigned long long)(idx ^ 0xFFFFFFFFu);
      atomicAdd(&hist[(size_t)img * 65536 + (bits >> 16)], 1u);
    }
  }
  __syncthreads();
  unsigned total = lcnt; if (total > SBUFN) total = SBUFN;
  if (tid == 0) gbase = atomicAdd(&scnt[img * CSTRIDE], total);
  __syncthreads();
  unsigned gb = gbase;
  for (unsigned i = tid; i < total; i += 512) {
    unsigned p = gb + i;
    if (p < SCAP) surv[(size_t)img * SCAP + p] = sbuf[i];
  }
}

__global__ void k_thresh(const unsigned* __restrict__ hist, unsigned* Tb, unsigned* needb) {
  int img = blockIdx.x;
  const unsigned* h = hist + (size_t)img * 65536;
  __shared__ unsigned part[256];
  __shared__ unsigned scan[257];
  int t = threadIdx.x;
  unsigned s = 0;
  for (int k = 0; k < 256; k++) {
    int bin = 65535 - (t * 256 + k);
    s += (bin == 0) ? 0x00100000u : h[bin];
  }
  part[t] = s; __syncthreads();
  if (t == 0) {
    unsigned c = 0;
    for (int k = 0; k < 256; k++) { scan[k] = c; c += part[k]; }
    scan[256] = c;
  }
  __syncthreads();
  unsigned pre = scan[t];
  if (pre < MK && pre + part[t] >= MK) {
    unsigned c = pre;
    for (int k = 0; k < 256; k++) {
      int bin = 65535 - (t * 256 + k);
      unsigned cnt = (bin == 0) ? 0x00100000u : h[bin];
      if (c + cnt >= MK) { Tb[img * CSTRIDE] = (unsigned)bin; needb[img * CSTRIDE] = MK - c; break; }
      c += cnt;
    }
  }
}

// compaction from survivor list
__global__ void k_collect(const unsigned long long* __restrict__ surv,
                          const unsigned* __restrict__ scnt,
                          const unsigned* __restrict__ Tb,
                          unsigned* selcnt, unsigned* sel,
                          unsigned* bcnt, unsigned long long* bnd) {
  int blk = blockIdx.x;
  int img = blk >> 7;
  int i = (blk & 127) * 256 + threadIdx.x;
  unsigned cnt = scnt[img * CSTRIDE]; if (cnt > SCAP) cnt = SCAP;
  unsigned long long entry = ((unsigned)i < cnt) ? surv[(size_t)img * SCAP + i] : 0ull;
  unsigned bits = (unsigned)(entry >> 32);
  unsigned bin = bits >> 16;
  unsigned T = Tb[img * CSTRIDE];
  bool ok = (unsigned)i < cnt;
  bool c1 = ok && (bin > T);
  bool c2 = ok && (bin == T);
  int lane = threadIdx.x & 63;
  unsigned long long lowmask = (1ull << lane) - 1ull;

  unsigned long long m1 = __ballot(c1);
  if (m1) {
    int leader = __ffsll(m1) - 1;
    unsigned base = 0;
    if (lane == leader) base = atomicAdd(&selcnt[img * CSTRIDE], (unsigned)__popcll(m1));
    base = __shfl(base, leader);
    if (c1) {
      unsigned p = base + (unsigned)__popcll(m1 & lowmask);
      if (p < MK) sel[img * MK + p] = (unsigned)(entry & 0xFFFFFFFFull) ^ 0xFFFFFFFFu;
    }
  }
  unsigned long long m2 = __ballot(c2);
  if (m2) {
    int leader = __ffsll(m2) - 1;
    unsigned base = 0;
    if (lane == leader) base = atomicAdd(&bcnt[img * CSTRIDE], (unsigned)__popcll(m2));
    base = __shfl(base, leader);
    if (c2) {
      unsigned p = base + (unsigned)__popcll(m2 & lowmask);
      if (p < CAPB) bnd[(size_t)img * CAPB + p] = entry;
    }
  }
}

__global__ void __launch_bounds__(1024)
k_finsel(const unsigned long long* __restrict__ bnd, const unsigned* bcnt,
         const unsigned* needb, const unsigned* selcnt, unsigned* sel) {
  int img = blockIdx.x;
  __shared__ unsigned long long key[CAPB];
  unsigned bn = bcnt[img * CSTRIDE];
  int n = (bn < CAPB) ? (int)bn : CAPB;
  int np2 = 2;
  while (np2 < n) np2 <<= 1;
  int t = threadIdx.x;
  for (int k = t; k < np2; k += 1024)
    key[k] = (k < n) ? bnd[(size_t)img * CAPB + k] : 0ull;
  __syncthreads();
  for (int sz = 2; sz <= np2; sz <<= 1) {
    for (int st = sz >> 1; st > 0; st >>= 1) {
      for (int i = t; i < np2; i += 1024) {
        int l = i ^ st;
        if (l > i) {
          unsigned long long a = key[i], b = key[l];
          bool up = ((i & sz) == 0);
          if (up ? (a < b) : (a > b)) { key[i] = b; key[l] = a; }
        }
      }
      __syncthreads();
    }
  }
  unsigned c1 = selcnt[img * CSTRIDE]; if (c1 > MK) c1 = MK;
  unsigned need = needb[img * CSTRIDE];
  unsigned kk = need; if (kk > MK - c1) kk = MK - c1;
  for (unsigned m = t; m < MK - c1; m += 1024) {
    unsigned v = 0u;
    if (m < kk && m < (unsigned)n)
      v = (unsigned)(key[m] & 0xFFFFFFFFull) ^ 0xFFFFFFFFu;
    sel[img * MK + c1 + m] = v;
  }
}

// ---------- sparse loss ----------
__global__ void k_prep(const unsigned* __restrict__ sel, const float* __restrict__ scoremap,
                       const float* __restrict__ gtA, const float* __restrict__ gtB,
                       const float* __restrict__ vA, const float* __restrict__ vB,
                       float2* pp, float* wx, float* wy, float* lg, float* sl) {
  int t = blockIdx.x * 256 + threadIdx.x;  // 0..32767
  int img = t >> 11;
  unsigned idx = sel[t] & (HW_ - 1);
  int h = idx >> 9, w = idx & 511;
  pp[t] = make_float2((w + 0.5f) * (2.0f / 512.0f) - 1.0f,
                      (h + 0.5f) * (2.0f / 512.0f) - 1.0f);
  int b = (img < 8) ? img : img - 8;
  const float* gt = (img < 8) ? gtA : gtB;
  const float* vv = (img < 8) ? vA : vB;
  size_t pix = (size_t)b * HW_ + idx;
  float2 gxy = *(const float2*)(gt + pix * 4 + 2);
  wx[t] = gxy.x;
  wy[t] = gxy.y;
  lg[t] = (vv[pix] > 0.0f) ? 1.0f : 0.0f;
  sl[t] = scoremap[(size_t)img * HW_ + idx];
}

// split 4-way over opponents, 8 independent min accumulators per thread
__global__ void __launch_bounds__(256)
k_mindist(const float2* __restrict__ pp,
          const float* __restrict__ wx, const float* __restrict__ wy,
          float* pmin) {
  __shared__ float2 opp[512];
  int blk = blockIdx.x;
  int img = blk >> 5;
  int qc = (blk >> 2) & 7;
  int oc = blk & 3;
  const float2* ob = pp + (size_t)(img ^ 8) * MK + oc * 512;
  for (int k = threadIdx.x; k < 512; k += 256) opp[k] = ob[k];
  __syncthreads();
  int m = img * MK + qc * 256 + threadIdx.x;
  float ax = wx[m], ay = wy[m];
  float d[8];
#pragma unroll
  for (int u = 0; u < 8; u++) d[u] = 3.4e38f;
  for (int n = 0; n < 512; n += 8) {
#pragma unroll
    for (int u = 0; u < 8; u++) {
      float2 o = opp[n + u];
      float dx = ax - o.x, dy = ay - o.y;
      d[u] = fminf(d[u], fmaf(dx, dx, dy * dy));
    }
  }
  float d2 = fminf(fminf(fminf(d[0], d[1]), fminf(d[2], d[3])),
                   fminf(fminf(d[4], d[5]), fminf(d[6], d[7])));
  pmin[oc * (NIMG * MK) + m] = d2;
}

__global__ void __launch_bounds__(1024)
k_loss(const float* __restrict__ sl, const float* __restrict__ lg,
       const float* __restrict__ pmin, float* sacc) {
  int img = blockIdx.x;
  __shared__ float red[1024];
  int t = threadIdx.x;
  int i0 = img * MK + t, i1 = i0 + 1024;
  float s0 = sl[i0], s1 = sl[i1];
  float g0 = lg[i0], g1 = lg[i1];
  float l0 = (g0 > 0.0f) ? s0 : -1e9f;
  float l1 = (g1 > 0.0f) ? s1 : -1e9f;
  float mx = brmax<1024>(fmaxf(l0, l1), red);
  float se = brsum<1024>(expf(l0 - mx) + expf(l1 - mx), red);
  float lse = mx + logf(se);
  const int ST = NIMG * MK;
  float a = 0.0f;
  if (g0 > 0.0f) {
    float mn = fminf(fminf(pmin[i0], pmin[ST + i0]),
                     fminf(pmin[2 * ST + i0], pmin[3 * ST + i0]));
    float r0 = expf(-100.0f * sqrtf(mn + 1e-12f));
    a += r0 * (s0 - lse);
  }
  if (g1 > 0.0f) {
    float mn = fminf(fminf(pmin[i1], pmin[ST + i1]),
                     fminf(pmin[2 * ST + i1], pmin[3 * ST + i1]));
    float r1 = expf(-100.0f * sqrtf(mn + 1e-12f));
    a += r1 * (s1 - lse);
  }
  float tot = brsum<1024>(a, red);
  if (t == 0) atomicAdd(sacc, -tot);
}

__global__ void k_out(const float* macc, const float* sacc, float* out) {
  out[0] = sacc[0] + macc[0] * (1.0f / 16.0f);
}

// ---------- launch ----------
extern "C" void kernel_launch(void* const* d_in, const int* in_sizes, int n_in,
                              void* d_out, int out_size, void* d_ws, size_t ws_size,
                              hipStream_t stream) {
  const float* scoremap = (const float*)d_in[0];
  const float* gtA = (const float*)d_in[1];
  const float* gtB = (const float*)d_in[2];
  const float* vA  = (const float*)d_in[3];
  const float* vB  = (const float*)d_in[4];
  const float* hd  = (const float*)d_in[5];

  char* ws = (char*)d_ws;
  float* A  = (float*)(ws);
  float* B1 = (float*)(ws + OFF_B1);

  char* sm = ws + OFF_SMALL;
  float*    sume   = (float*)(sm + 0);
  float*    sumS   = (float*)(sm + 2048);
  float*    Zb     = (float*)(sm + 4096);
  unsigned* Tb     = (unsigned*)(sm + 6144);
  unsigned* needb  = (unsigned*)(sm + 8192);
  unsigned* selcnt = (unsigned*)(sm + 10240);
  unsigned* bcnt   = (unsigned*)(sm + 12288);
  float*    macc   = (float*)(sm + 14336);
  float*    sacc   = (float*)(sm + 14464);
  unsigned* scnt   = (unsigned*)(sm + 16384);

  unsigned* hist = (unsigned*)(ws + OFF_HIST);
  unsigned long long* surv = (unsigned long long*)(ws + OFF_SURV);
  unsigned* sel  = (unsigned*)(ws + OFF_SEL);
  unsigned long long* bnd = (unsigned long long*)(ws + OFF_BND);
  float2* pp = (float2*)(ws + OFF_PP);
  float* wx = (float*)(ws + OFF_WXp);
  float* wy = (float*)(ws + OFF_WYp);
  float* lg = (float*)(ws + OFF_LG);
  float* sl = (float*)(ws + OFF_SL);
  float* pmin = (float*)(ws + OFF_PMIN);
  float* B2 = (float*)(ws + 33554432);

  float* out = (float*)d_out;

  hipMemsetAsync(sm, 0, 32768, stream);

  // pass 1: exp + sume/sumS/Zb (separable conv sums)
  k_pre<<<4096, 256, 0, stream>>>(scoremap, hd, A, sume, sumS, Zb);

  // matchability
  k_hconv<<<8192, 256, 0, stream>>>(A, hd, sume, B1, B2);
  k_match<<<1024, 256, 0, stream>>>(B1, B2, sume, sumS, Zb, macc);

  // coverage conv (h) -> B1'; hist/surv live in B2 (dead after k_match)
  k_h51<<<8192, 256, 0, stream>>>(A, sume, B1);
  hipMemsetAsync(ws + OFF_HIST, 0, (size_t)16 * 65536 * 4, stream);

  // fused vconv+reweight+NMS+compaction+hist (512 threads, scalar LDS)
  k_smwnms<<<1024, 512, 0, stream>>>(A, sume, B1, surv, scnt, hist);
  k_thresh<<<16, 256, 0, stream>>>(hist, Tb, needb);
  k_collect<<<2048, 256, 0, stream>>>(surv, scnt, Tb, selcnt, sel, bcnt, bnd);
  k_finsel<<<16, 1024, 0, stream>>>(bnd, bcnt, needb, selcnt, sel);

  // sparse loss
  k_prep<<<128, 256, 0, stream>>>(sel, scoremap, gtA, gtB, vA, vB, pp, wx, wy, lg, sl);
  k_mindist<<<512, 256, 0, stream>>>(pp, wx, wy, pmin);
  k_loss<<<16, 1024, 0, stream>>>(sl, lg, pmin, sacc);
  k_out<<<1, 1, 0, stream>>>(macc, sacc, out);
}

// Round 9
// 327.384 us; speedup vs baseline: 1.2420x; 1.0242x over previous
//
#include <hip/hip_runtime.h>

#define HH 512
#define WW 512
#define HW_ 262144
#define NIMG 16
#define MK 2048
#define CAPB 4096
#define SCAP 32768   // survivor capacity per image
#define SBUFN 768    // per-block survivor staging (>=484 worst-case maxima per 64x64 tile)

static constexpr size_t OFF_B1    = 16777216;   // 16MB
static constexpr size_t OFF_B2    = 33554432;   // 32MB
static constexpr size_t OFF_SMALL = 50331648;   // 48MB
// regions inside buffer A (all written only after A's last read in k_smwnms):
static constexpr size_t OFF_SEL  = 4194304;
static constexpr size_t OFF_BND  = 4325376;
static constexpr size_t OFF_PP   = 4849664;
static constexpr size_t OFF_WXp  = 5111808;
static constexpr size_t OFF_WYp  = 5242880;
static constexpr size_t OFF_LG   = 5373952;
static constexpr size_t OFF_SL   = 5505024;
static constexpr size_t OFF_PMIN = 5636096;
// regions inside B2 (B2 dead after k_match):
static constexpr size_t OFF_HIST = 33554432;            // 4MB
static constexpr size_t OFF_SURV = 33554432 + 4194304;  // 4MB

// per-image counters padded to 128B to kill cacheline serialization
#define CSTRIDE 32

// ---------- helpers ----------
__device__ __forceinline__ float wred64(float v) {
  for (int m = 1; m < 64; m <<= 1) v += __shfl_xor(v, m);
  return v;
}

__device__ __forceinline__ void g25_wave0(float* g) {
  int t = threadIdx.x;
  if (t < 64) {
    float raw = 0.0f;
    if (t < 25) {
      float x = -1.0f + (float)t * (2.0f / 24.0f);
      raw = expf(-(x * x) / 0.5f);
    }
    float s = raw;
    for (int m = 1; m < 64; m <<= 1) s += __shfl_xor(s, m);
    if (t < 25) g[t] = raw / s;
  }
}
__device__ __forceinline__ void w51_wave0(float* wc) {
  int t = threadIdx.x;
  if (t < 51) {
    float x = -2.0f + (float)t * (4.0f / 50.0f);
    wc[t] = expf(-x * x);
  }
}

template<int B>
__device__ __forceinline__ float brsum(float v, float* red) {
  int t = threadIdx.x;
  red[t] = v; __syncthreads();
  for (int s = B >> 1; s > 0; s >>= 1) {
    if (t < s) red[t] += red[t + s];
    __syncthreads();
  }
  float r = red[0]; __syncthreads();
  return r;
}
template<int B>
__device__ __forceinline__ float brmax(float v, float* red) {
  int t = threadIdx.x;
  red[t] = v; __syncthreads();
  for (int s = B >> 1; s > 0; s >>= 1) {
    if (t < s) red[t] = fmaxf(red[t], red[t + s]);
    __syncthreads();
  }
  float r = red[0]; __syncthreads();
  return r;
}

// ---------- pass 1: exp + all three global sums (separable conv trick) ----------
__global__ void __launch_bounds__(256)
k_pre(const float* __restrict__ x, const float* __restrict__ hd, float* A,
      float* sume, float* sumS, float* Zb) {
  __shared__ float g[25];
  __shared__ float red[12];
  int tid = threadIdx.x;
  g25_wave0(g);
  size_t base = (size_t)blockIdx.x * 1024;
  size_t e = base + tid * 4;
  float4 xs = *(const float4*)(x + e);
  float4 hs = *(const float4*)(hd + e);
  __syncthreads();
  int rem = (int)(e & (HW_ - 1));
  int y = rem >> 9, x0 = rem & 511;
  float wv = 0.0f;
  {
    int k0 = y - 499; if (k0 < 0) k0 = 0;
    int k1 = y + 12;  if (k1 > 24) k1 = 24;
    for (int k = k0; k <= k1; k++) wv += g[k];
  }
  float cwv[4], cpv[4];
  {
    int lo = x0 - 487; if (lo < 0) lo = 0;
    int hi = x0;       if (hi > 24) hi = 24;
    float c = 0.0f;
    for (int d = lo; d <= hi; d++) c += g[d];
    cwv[0] = c;
    for (int q = 1; q < 4; q++) {
      int i = x0 + q;
      if (i <= 24) c += g[i];
      if (i >= 488) c -= g[i - 488];
      cwv[q] = c;
    }
  }
  {
    int lo = x0 - 499; if (lo < 0) lo = 0;
    int hi = x0 + 12;  if (hi > 24) hi = 24;
    float c = 0.0f;
    for (int d = lo; d <= hi; d++) c += g[d];
    cpv[0] = c;
    for (int q = 1; q < 4; q++) {
      int i = x0 + q;
      if (i + 12 <= 24) c += g[i + 12];
      if (i >= 500) c -= g[i - 500];
      cpv[q] = c;
    }
  }
  float e0 = expf(xs.x), e1 = expf(xs.y), e2 = expf(xs.z), e3 = expf(xs.w);
  *(float4*)(A + e) = make_float4(e0, e1, e2, e3);
  float r0 = (e0 + e1) + (e2 + e3);
  float r1 = (e0 * cwv[0] + e1 * cwv[1] + e2 * cwv[2] + e3 * cwv[3]) * wv;
  float r2 = (hs.x * cpv[0] + hs.y * cpv[1] + hs.z * cpv[2] + hs.w * cpv[3]) * wv;
  r0 = wred64(r0); r1 = wred64(r1); r2 = wred64(r2);
  int wid = tid >> 6;
  if ((tid & 63) == 0) { red[wid] = r0; red[4 + wid] = r1; red[8 + wid] = r2; }
  __syncthreads();
  if (tid == 0) {
    int img = (int)(base >> 18);
    atomicAdd(&sume[img * CSTRIDE], red[0] + red[1] + red[2] + red[3]);
    atomicAdd(&sumS[img * CSTRIDE], red[4] + red[5] + red[6] + red[7]);
    atomicAdd(&Zb[img * CSTRIDE], red[8] + red[9] + red[10] + red[11]);
  }
}

// ---------- horizontal convs: pure streaming, one row per block ----------
__global__ void __launch_bounds__(256)
k_hconv(const float* __restrict__ A, const float* __restrict__ hd,
        const float* __restrict__ sume, float* b1, float* b2) {
  __shared__ __align__(16) float ta[512];
  __shared__ __align__(16) float th[536];
  __shared__ float g[25];
  int tid = threadIdx.x;
  int blk = blockIdx.x;
  int img = blk >> 9;
  size_t rowoff = (size_t)blk * 512;
  g25_wave0(g);
  ((float2*)ta)[tid] = *(const float2*)(A + rowoff + tid * 2);
  ((float2*)(th + 12))[tid] = *(const float2*)(hd + rowoff + tid * 2);
  if (tid < 12) { th[tid] = 0.0f; th[524 + tid] = 0.0f; }
  __syncthreads();
  float inv = 1.0f / sume[img * CSTRIDE];
  int j = 2 * tid;
  float v1a = 0.0f, v1b = 0.0f;
  if (tid >= 6 && tid <= 249) {
    float w[26];
#pragma unroll
    for (int d = 0; d < 26; d++) w[d] = ta[j - 12 + d];
#pragma unroll
    for (int d = 0; d < 25; d++) {
      v1a = fmaf(g[d], w[d], v1a);
      v1b = fmaf(g[d], w[d + 1], v1b);
    }
  }
  float v2a = 0.0f, v2b = 0.0f;
  {
    float u[26];
#pragma unroll
    for (int d = 0; d < 26; d++) u[d] = th[j + d];
#pragma unroll
    for (int d = 0; d < 25; d++) {
      v2a = fmaf(g[d], u[d], v2a);
      v2b = fmaf(g[d], u[d + 1], v2b);
    }
  }
  ((float2*)b1)[blk * 256 + tid] = make_float2(v1a * inv, v1b * inv);
  ((float2*)b2)[blk * 256 + tid] = make_float2(v2a, v2b);
}

// fused vertical convs + KL reduction, LDS-tiled, register-tiled R=4
__global__ void __launch_bounds__(256)
k_match(const float* __restrict__ b1, const float* __restrict__ b2,
        const float* __restrict__ sume, const float* sumS, const float* Zb,
        float* macc) {
  __shared__ float g[25];
  __shared__ float t1[88 * 64];
  __shared__ float t2[88 * 64];
  __shared__ float red4[4];
  g25_wave0(g);
  int blk = blockIdx.x;
  int img = blk >> 6;
  int ty = (blk >> 3) & 7;
  int tx = blk & 7;
  int y0 = ty * 64, x0 = tx * 64;
  const float* base1 = b1 + (size_t)img * HW_;
  const float* base2 = b2 + (size_t)img * HW_;
  for (int i = threadIdx.x; i < 88 * 64; i += 256) {
    int r = i >> 6, c = i & 63;
    int y = y0 + r - 12;
    float v1 = 0.0f, v2 = 0.0f;
    if (y >= 0 && y < 512) {
      size_t o = (size_t)y * 512 + x0 + c;
      v1 = base1[o]; v2 = base2[o];
    }
    t1[i] = v1; t2[i] = v2;
  }
  __syncthreads();
  float Z = Zb[img * CSTRIDE];
  float inv = 1.0f / sume[img * CSTRIDE];
  float logS = logf(sumS[img * CSTRIDE] * inv + (float)HW_ * 1e-8f);
  float acc = 0.0f;
  // work: 16 row-groups (R=4) x 64 cols; each input read once, feeds 4 accs
  for (int w = threadIdx.x; w < 1024; w += 256) {
    int rg = w >> 6, c = w & 63;
    int r0 = rg * 4;
    float s[4] = {0.f, 0.f, 0.f, 0.f};
    float d[4] = {0.f, 0.f, 0.f, 0.f};
#pragma unroll
    for (int i = 0; i < 28; i++) {
      float v1 = t1[(r0 + i) * 64 + c];
      float v2 = t2[(r0 + i) * 64 + c];
#pragma unroll
      for (int jj = 0; jj < 4; jj++) {
        if (i >= jj && i - jj < 25) {
          s[jj] = fmaf(g[i - jj], v1, s[jj]);
          d[jj] = fmaf(g[i - jj], v2, d[jj]);
        }
      }
    }
#pragma unroll
    for (int jj = 0; jj < 4; jj++) {
      float p = d[jj] / Z;
      if (p > 0.0f)
        acc += p * (logf(fmaxf(p, 1e-30f)) - (logf(s[jj] + 1e-8f) - logS));
    }
  }
  acc = wred64(acc);
  if ((threadIdx.x & 63) == 0) red4[threadIdx.x >> 6] = acc;
  __syncthreads();
  if (threadIdx.x == 0)
    atomicAdd(macc, red4[0] + red4[1] + red4[2] + red4[3]);
}

// ---------- keypoint sampling ----------
__global__ void __launch_bounds__(256)
k_h51(const float* __restrict__ A, const float* __restrict__ sume, float* out) {
  __shared__ float wc[51];
  __shared__ __align__(16) float ta[564];
  int tid = threadIdx.x;
  int blk = blockIdx.x;
  int img = blk >> 9;
  size_t rowoff = (size_t)blk * 512;
  w51_wave0(wc);
  float s1 = 1e4f / sume[img * CSTRIDE];
  for (int i = tid; i < 562; i += 256) {
    int j = i - 25;
    ta[i] = ((unsigned)j < 512u) ? fmaf(A[rowoff + j], s1, 1e-2f) : 0.0f;
  }
  __syncthreads();
  int j = 2 * tid;
  float w[52];
#pragma unroll
  for (int d = 0; d < 52; d++) w[d] = ta[j + d];
  float va = 0.0f, vb = 0.0f;
#pragma unroll
  for (int d = 0; d < 51; d++) {
    va = fmaf(wc[d], w[d], va);
    vb = fmaf(wc[d], w[d + 1], vb);
  }
  ((float2*)out)[blk * 256 + tid] = make_float2(va, vb);
}

// fused: vertical 51-tap (register-tiled R=4) + coverage reweight +
// separable 5x5 NMS + block-aggregated survivor compaction + histogram.
__global__ void __launch_bounds__(512)
k_smwnms(const float* __restrict__ A, const float* __restrict__ sume,
         const float* __restrict__ b1,
         unsigned long long* surv, unsigned* scnt, unsigned* hist) {
  __shared__ float wc[51];
  __shared__ float tb1[118 * 68];
  __shared__ float tsm[68 * 68];
  __shared__ unsigned long long sbuf[SBUFN];
  __shared__ unsigned lcnt;
  __shared__ unsigned gbase;
  float* hm = tb1;  // alias: tb1 dead after conv phase; hm is 68x64
  int tid = threadIdx.x;
  w51_wave0(wc);
  if (tid == 0) lcnt = 0;
  int blk = blockIdx.x;
  int img = blk >> 6;
  int ty = (blk >> 3) & 7;
  int tx = blk & 7;
  int y0 = ty * 64, x0 = tx * 64;
  const float* base = b1 + (size_t)img * HW_;
  // B1 rows y0-27..y0+90, cols x0-2..x0+65 (zero OOB)
  for (int i = tid; i < 118 * 68; i += 512) {
    int r = i / 68, c = i - r * 68;
    int y = y0 + r - 27, x = x0 + c - 2;
    tb1[i] = (y >= 0 && y < 512 && x >= 0 && x < 512)
                 ? base[(size_t)y * 512 + x] : 0.0f;
  }
  __syncthreads();
  float inv = 1.0f / sume[img * CSTRIDE];
  const float* abase = A + (size_t)img * HW_;
  // conv on 68x68 halo tile, register-tiled: 17 row-groups (R=4) x 68 cols
  for (int w = tid; w < 68 * 17; w += 512) {
    int rg = w / 68, c = w - rg * 68;
    int r0 = rg * 4;
    float a[4] = {0.f, 0.f, 0.f, 0.f};
#pragma unroll
    for (int i = 0; i < 54; i++) {
      float v = tb1[(r0 + i) * 68 + c];
#pragma unroll
      for (int jj = 0; jj < 4; jj++) {
        if (i >= jj && i - jj < 51) a[jj] = fmaf(wc[i - jj], v, a[jj]);
      }
    }
#pragma unroll
    for (int jj = 0; jj < 4; jj++) {
      int r = r0 + jj;
      int y = y0 + r - 2, x = x0 + c - 2;
      float res = -3.4e38f;
      if (y >= 0 && y < 512 && x >= 0 && x < 512)
        res = (abase[(size_t)y * 512 + x] * inv) / sqrtf(a[jj] + 1e-8f);
      tsm[r * 68 + c] = res;
    }
  }
  __syncthreads();
  // separable NMS pass 1: horizontal 5-max  hm[r][c]=max(tsm[r][c..c+4])
  for (int i = tid; i < 68 * 64; i += 512) {
    int r = i >> 6, c = i & 63;
    const float* row = tsm + r * 68 + c;
    float m = fmaxf(fmaxf(row[0], row[1]), fmaxf(row[2], fmaxf(row[3], row[4])));
    hm[i] = m;
  }
  __syncthreads();
  // pass 2: vertical 5-max + keep test; LDS-atomic staging of survivors
  for (int k0 = 0; k0 < 8; k0++) {
    int i = tid + k0 * 512;
    int r = i >> 6, c = i & 63;
    float v = tsm[(r + 2) * 68 + (c + 2)];
    float M = hm[r * 64 + c];
    M = fmaxf(M, hm[(r + 1) * 64 + c]);
    M = fmaxf(M, hm[(r + 2) * 64 + c]);
    M = fmaxf(M, hm[(r + 3) * 64 + c]);
    M = fmaxf(M, hm[(r + 4) * 64 + c]);
    bool keep = (v == M) && (v != 0.0f);
    if (keep) {
      unsigned p = atomicAdd(&lcnt, 1u);   // LDS atomic: cheap
      unsigned bits = __float_as_uint(v);
      unsigned idx = (unsigned)((y0 + r) * 512 + x0 + c);
      if (p < SBUFN)
        sbuf[p] = ((unsigned long long)bits << 32) |
                  (unsigned long long)(idx ^ 0xFFFFFFFFu);
      atomicAdd(&hist[(size_t)img * 65536 + (bits >> 16)], 1u);
    }
  }
  __syncthreads();
  unsigned total = lcnt; if (total > SBUFN) total = SBUFN;
  if (tid == 0) gbase = atomicAdd(&scnt[img * CSTRIDE], total);
  __syncthreads();
  unsigned gb = gbase;
  for (unsigned i = tid; i < total; i += 512) {
    unsigned p = gb + i;
    if (p < SCAP) surv[(size_t)img * SCAP + p] = sbuf[i];
  }
}

__global__ void k_thresh(const unsigned* __restrict__ hist, unsigned* Tb, unsigned* needb) {
  int img = blockIdx.x;
  const unsigned* h = hist + (size_t)img * 65536;
  __shared__ unsigned part[256];
  __shared__ unsigned scan[257];
  int t = threadIdx.x;
  unsigned s = 0;
  for (int k = 0; k < 256; k++) {
    int bin = 65535 - (t * 256 + k);
    s += (bin == 0) ? 0x00100000u : h[bin];
  }
  part[t] = s; __syncthreads();
  if (t == 0) {
    unsigned c = 0;
    for (int k = 0; k < 256; k++) { scan[k] = c; c += part[k]; }
    scan[256] = c;
  }
  __syncthreads();
  unsigned pre = scan[t];
  if (pre < MK && pre + part[t] >= MK) {
    unsigned c = pre;
    for (int k = 0; k < 256; k++) {
      int bin = 65535 - (t * 256 + k);
      unsigned cnt = (bin == 0) ? 0x00100000u : h[bin];
      if (c + cnt >= MK) { Tb[img * CSTRIDE] = (unsigned)bin; needb[img * CSTRIDE] = MK - c; break; }
      c += cnt;
    }
  }
}

// compaction from survivor list
__global__ void k_collect(const unsigned long long* __restrict__ surv,
                          const unsigned* __restrict__ scnt,
                          const unsigned* __restrict__ Tb,
                          unsigned* selcnt, unsigned* sel,
                          unsigned* bcnt, unsigned long long* bnd) {
  int blk = blockIdx.x;
  int img = blk >> 7;
  int i = (blk & 127) * 256 + threadIdx.x;
  unsigned cnt = scnt[img * CSTRIDE]; if (cnt > SCAP) cnt = SCAP;
  unsigned long long entry = ((unsigned)i < cnt) ? surv[(size_t)img * SCAP + i] : 0ull;
  unsigned bits = (unsigned)(entry >> 32);
  unsigned bin = bits >> 16;
  unsigned T = Tb[img * CSTRIDE];
  bool ok = (unsigned)i < cnt;
  bool c1 = ok && (bin > T);
  bool c2 = ok && (bin == T);
  int lane = threadIdx.x & 63;
  unsigned long long lowmask = (1ull << lane) - 1ull;

  unsigned long long m1 = __ballot(c1);
  if (m1) {
    int leader = __ffsll(m1) - 1;
    unsigned base = 0;
    if (lane == leader) base = atomicAdd(&selcnt[img * CSTRIDE], (unsigned)__popcll(m1));
    base = __shfl(base, leader);
    if (c1) {
      unsigned p = base + (unsigned)__popcll(m1 & lowmask);
      if (p < MK) sel[img * MK + p] = (unsigned)(entry & 0xFFFFFFFFull) ^ 0xFFFFFFFFu;
    }
  }
  unsigned long long m2 = __ballot(c2);
  if (m2) {
    int leader = __ffsll(m2) - 1;
    unsigned base = 0;
    if (lane == leader) base = atomicAdd(&bcnt[img * CSTRIDE], (unsigned)__popcll(m2));
    base = __shfl(base, leader);
    if (c2) {
      unsigned p = base + (unsigned)__popcll(m2 & lowmask);
      if (p < CAPB) bnd[(size_t)img * CAPB + p] = entry;
    }
  }
}

__global__ void __launch_bounds__(1024)
k_finsel(const unsigned long long* __restrict__ bnd, const unsigned* bcnt,
         const unsigned* needb, const unsigned* selcnt, unsigned* sel) {
  int img = blockIdx.x;
  __shared__ unsigned long long key[CAPB];
  unsigned bn = bcnt[img * CSTRIDE];
  int n = (bn < CAPB) ? (int)bn : CAPB;
  int np2 = 2;
  while (np2 < n) np2 <<= 1;
  int t = threadIdx.x;
  for (int k = t; k < np2; k += 1024)
    key[k] = (k < n) ? bnd[(size_t)img * CAPB + k] : 0ull;
  __syncthreads();
  for (int sz = 2; sz <= np2; sz <<= 1) {
    for (int st = sz >> 1; st > 0; st >>= 1) {
      for (int i = t; i < np2; i += 1024) {
        int l = i ^ st;
        if (l > i) {
          unsigned long long a = key[i], b = key[l];
          bool up = ((i & sz) == 0);
          if (up ? (a < b) : (a > b)) { key[i] = b; key[l] = a; }
        }
      }
      __syncthreads();
    }
  }
  unsigned c1 = selcnt[img * CSTRIDE]; if (c1 > MK) c1 = MK;
  unsigned need = needb[img * CSTRIDE];
  unsigned kk = need; if (kk > MK - c1) kk = MK - c1;
  for (unsigned m = t; m < MK - c1; m += 1024) {
    unsigned v = 0u;
    if (m < kk && m < (unsigned)n)
      v = (unsigned)(key[m] & 0xFFFFFFFFull) ^ 0xFFFFFFFFu;
    sel[img * MK + c1 + m] = v;
  }
}

// ---------- sparse loss ----------
__global__ void k_prep(const unsigned* __restrict__ sel, const float* __restrict__ scoremap,
                       const float* __restrict__ gtA, const float* __restrict__ gtB,
                       const float* __restrict__ vA, const float* __restrict__ vB,
                       float2* pp, float* wx, float* wy, float* lg, float* sl) {
  int t = blockIdx.x * 256 + threadIdx.x;  // 0..32767
  int img = t >> 11;
  unsigned idx = sel[t] & (HW_ - 1);
  int h = idx >> 9, w = idx & 511;
  pp[t] = make_float2((w + 0.5f) * (2.0f / 512.0f) - 1.0f,
                      (h + 0.5f) * (2.0f / 512.0f) - 1.0f);
  int b = (img < 8) ? img : img - 8;
  const float* gt = (img < 8) ? gtA : gtB;
  const float* vv = (img < 8) ? vA : vB;
  size_t pix = (size_t)b * HW_ + idx;
  float2 gxy = *(const float2*)(gt + pix * 4 + 2);
  wx[t] = gxy.x;
  wy[t] = gxy.y;
  lg[t] = (vv[pix] > 0.0f) ? 1.0f : 0.0f;
  sl[t] = scoremap[(size_t)img * HW_ + idx];
}

// split 4-way over opponents, 8 independent min accumulators per thread
__global__ void __launch_bounds__(256)
k_mindist(const float2* __restrict__ pp,
          const float* __restrict__ wx, const float* __restrict__ wy,
          float* pmin) {
  __shared__ float2 opp[512];
  int blk = blockIdx.x;
  int img = blk >> 5;
  int qc = (blk >> 2) & 7;
  int oc = blk & 3;
  const float2* ob = pp + (size_t)(img ^ 8) * MK + oc * 512;
  for (int k = threadIdx.x; k < 512; k += 256) opp[k] = ob[k];
  __syncthreads();
  int m = img * MK + qc * 256 + threadIdx.x;
  float ax = wx[m], ay = wy[m];
  float d[8];
#pragma unroll
  for (int u = 0; u < 8; u++) d[u] = 3.4e38f;
  for (int n = 0; n < 512; n += 8) {
#pragma unroll
    for (int u = 0; u < 8; u++) {
      float2 o = opp[n + u];
      float dx = ax - o.x, dy = ay - o.y;
      d[u] = fminf(d[u], fmaf(dx, dx, dy * dy));
    }
  }
  float d2 = fminf(fminf(fminf(d[0], d[1]), fminf(d[2], d[3])),
                   fminf(fminf(d[4], d[5]), fminf(d[6], d[7])));
  pmin[oc * (NIMG * MK) + m] = d2;
}

__global__ void __launch_bounds__(1024)
k_loss(const float* __restrict__ sl, const float* __restrict__ lg,
       const float* __restrict__ pmin, float* sacc) {
  int img = blockIdx.x;
  __shared__ float red[1024];
  int t = threadIdx.x;
  int i0 = img * MK + t, i1 = i0 + 1024;
  float s0 = sl[i0], s1 = sl[i1];
  float g0 = lg[i0], g1 = lg[i1];
  float l0 = (g0 > 0.0f) ? s0 : -1e9f;
  float l1 = (g1 > 0.0f) ? s1 : -1e9f;
  float mx = brmax<1024>(fmaxf(l0, l1), red);
  float se = brsum<1024>(expf(l0 - mx) + expf(l1 - mx), red);
  float lse = mx + logf(se);
  const int ST = NIMG * MK;
  float a = 0.0f;
  if (g0 > 0.0f) {
    float mn = fminf(fminf(pmin[i0], pmin[ST + i0]),
                     fminf(pmin[2 * ST + i0], pmin[3 * ST + i0]));
    float r0 = expf(-100.0f * sqrtf(mn + 1e-12f));
    a += r0 * (s0 - lse);
  }
  if (g1 > 0.0f) {
    float mn = fminf(fminf(pmin[i1], pmin[ST + i1]),
                     fminf(pmin[2 * ST + i1], pmin[3 * ST + i1]));
    float r1 = expf(-100.0f * sqrtf(mn + 1e-12f));
    a += r1 * (s1 - lse);
  }
  float tot = brsum<1024>(a, red);
  if (t == 0) atomicAdd(sacc, -tot);
}

__global__ void k_out(const float* macc, const float* sacc, float* out) {
  out[0] = sacc[0] + macc[0] * (1.0f / 16.0f);
}

// ---------- launch ----------
extern "C" void kernel_launch(void* const* d_in, const int* in_sizes, int n_in,
                              void* d_out, int out_size, void* d_ws, size_t ws_size,
                              hipStream_t stream) {
  const float* scoremap = (const float*)d_in[0];
  const float* gtA = (const float*)d_in[1];
  const float* gtB = (const float*)d_in[2];
  const float* vA  = (const float*)d_in[3];
  const float* vB  = (const float*)d_in[4];
  const float* hd  = (const float*)d_in[5];

  char* ws = (char*)d_ws;
  float* A  = (float*)(ws);
  float* B1 = (float*)(ws + OFF_B1);

  char* sm = ws + OFF_SMALL;
  float*    sume   = (float*)(sm + 0);
  float*    sumS   = (float*)(sm + 2048);
  float*    Zb     = (float*)(sm + 4096);
  unsigned* Tb     = (unsigned*)(sm + 6144);
  unsigned* needb  = (unsigned*)(sm + 8192);
  unsigned* selcnt = (unsigned*)(sm + 10240);
  unsigned* bcnt   = (unsigned*)(sm + 12288);
  float*    macc   = (float*)(sm + 14336);
  float*    sacc   = (float*)(sm + 14464);
  unsigned* scnt   = (unsigned*)(sm + 16384);

  unsigned* hist = (unsigned*)(ws + OFF_HIST);
  unsigned long long* surv = (unsigned long long*)(ws + OFF_SURV);
  unsigned* sel  = (unsigned*)(ws + OFF_SEL);
  unsigned long long* bnd = (unsigned long long*)(ws + OFF_BND);
  float2* pp = (float2*)(ws + OFF_PP);
  float* wx = (float*)(ws + OFF_WXp);
  float* wy = (float*)(ws + OFF_WYp);
  float* lg = (float*)(ws + OFF_LG);
  float* sl = (float*)(ws + OFF_SL);
  float* pmin = (float*)(ws + OFF_PMIN);
  float* B2 = (float*)(ws + 33554432);

  float* out = (float*)d_out;

  hipMemsetAsync(sm, 0, 32768, stream);

  // pass 1: exp + sume/sumS/Zb (separable conv sums)
  k_pre<<<4096, 256, 0, stream>>>(scoremap, hd, A, sume, sumS, Zb);

  // matchability
  k_hconv<<<8192, 256, 0, stream>>>(A, hd, sume, B1, B2);
  k_match<<<1024, 256, 0, stream>>>(B1, B2, sume, sumS, Zb, macc);

  // coverage conv (h) -> B1'; hist/surv live in B2 (dead after k_match)
  k_h51<<<8192, 256, 0, stream>>>(A, sume, B1);
  hipMemsetAsync(ws + OFF_HIST, 0, (size_t)16 * 65536 * 4, stream);

  // fused vconv+reweight+NMS+compaction+hist (register-tiled, separable NMS)
  k_smwnms<<<1024, 512, 0, stream>>>(A, sume, B1, surv, scnt, hist);
  k_thresh<<<16, 256, 0, stream>>>(hist, Tb, needb);
  k_collect<<<2048, 256, 0, stream>>>(surv, scnt, Tb, selcnt, sel, bcnt, bnd);
  k_finsel<<<16, 1024, 0, stream>>>(bnd, bcnt, needb, selcnt, sel);

  // sparse loss
  k_prep<<<128, 256, 0, stream>>>(sel, scoremap, gtA, gtB, vA, vB, pp, wx, wy, lg, sl);
  k_mindist<<<512, 256, 0, stream>>>(pp, wx, wy, pmin);
  k_loss<<<16, 1024, 0, stream>>>(sl, lg, pmin, sacc);
  k_out<<<1, 1, 0, stream>>>(macc, sacc, out);
}